// Round 1
// baseline (396.125 us; speedup 1.0000x reference)
//
#include <hip/hip_runtime.h>
#include <math.h>

// Problem constants: x[B=32][C=256][HW=3136], omega[256][8], rank q=8, niter=2.
#define HW   3136
#define NB   32      // batch (matrix cols of A: A is C x B)
#define NC   256     // channels (matrix rows of A)
#define NQ   8       // low rank
#define TM   16      // m-tile per block
#define CC   8       // c's per LDS chunk
#define SLABF (CC * NB * TM)   // 4096 floats per slab buffer

// ---- phase-B LDS layout (overlaps the phase-A slab; separated by barrier) ----
// YT: per-m 32x8 stored transposed-ish: addr = mi*265 + q*33 + b  (stride 265 odd -> mi hits distinct banks)
// WT: same layout at +4240
// SS: 8x8 scratch per m: addr = 8480 + mi*65 + k
#define YT_(mi,b,q) Sm[(mi)*265 + (q)*33 + (b)]
#define WT_(mi,b,q) Sm[4240 + (mi)*265 + (q)*33 + (b)]
#define SS_(mi,k)   Sm[8480 + (mi)*65 + (k)]
#define SMEMF 9520   // max(2*SLABF = 8192, 8480 + 16*65 = 9520)

__host__ __device__ constexpr int TRI(int i, int j) { return i*8 - (i*(i+1))/2 + j; } // i<=j, 36 slots

// ---- coalesced global->reg->LDS staging (slab layout [cc][b][mi], mi contiguous) ----
__device__ __forceinline__ void stage_load(float4* r, const float* __restrict__ xg,
                                           int c0, int m0, int t) {
#pragma unroll
  for (int i = 0; i < 4; ++i) {
    int id = t + i * 256;                 // 0..1023 float4's per chunk
    int cc = id >> 7, b = (id >> 2) & 31, mq = id & 3;
    r[i] = *reinterpret_cast<const float4*>(
        xg + (size_t)(b * NC + c0 + cc) * HW + m0 + mq * 4);
  }
}
__device__ __forceinline__ void stage_write(const float4* r, float* sl, int t) {
#pragma unroll
  for (int i = 0; i < 4; ++i) {
    int id = t + i * 256;
    int cc = id >> 7, b = (id >> 2) & 31, mq = id & 3;
    *reinterpret_cast<float4*>(sl + cc * (NB * TM) + b * TM + mq * 4) = r[i];
  }
}

// ---- replicated 8x8 Cholesky from SS (upper R; diag slot holds 1/R[i][i]) ----
__device__ __forceinline__ void chol8(const float* __restrict__ Sm, int mi, float* Rl) {
#pragma unroll
  for (int i = 0; i < 8; ++i) {
    float d = SS_(mi, i * 8 + i);
#pragma unroll
    for (int k = 0; k < 8; ++k) {
      if (k < i) { float rk = Rl[TRI(k, i)]; d = fmaf(-rk, rk, d); }
    }
    float rii = sqrtf(fmaxf(d, 1e-30f));
    float inv = 1.0f / rii;
    Rl[TRI(i, i)] = inv;
#pragma unroll
    for (int j = 0; j < 8; ++j) {
      if (j > i) {
        float v = SS_(mi, i * 8 + j);
#pragma unroll
        for (int k = 0; k < 8; ++k) {
          if (k < i) v = fmaf(-Rl[TRI(k, i)], Rl[TRI(k, j)], v);
        }
        Rl[TRI(i, j)] = v * inv;
      }
    }
  }
}

// rows r0,r0+1: dst = src * R^{-1}  (row-wise forward substitution)
__device__ __forceinline__ void trsm2rows(const float* __restrict__ srcB, float* __restrict__ dstB,
                                          int mi, int r0, const float* Rl) {
#pragma unroll
  for (int rr = 0; rr < 2; ++rr) {
    int r = r0 + rr;
    float yv[8], qv[8];
#pragma unroll
    for (int q = 0; q < 8; ++q) yv[q] = srcB[mi * 265 + q * 33 + r];
#pragma unroll
    for (int j = 0; j < 8; ++j) {
      float a = yv[j];
#pragma unroll
      for (int k = 0; k < 8; ++k) {
        if (k < j) a = fmaf(-qv[k], Rl[TRI(k, j)], a);
      }
      qv[j] = a * Rl[TRI(j, j)];
    }
#pragma unroll
    for (int q = 0; q < 8; ++q) dstB[mi * 265 + q * 33 + r] = qv[q];
  }
}

// one CholeskyQR pass in-place on YT (call twice for CholQR2)
__device__ __forceinline__ void cholqr_pass(float* __restrict__ Sm, int mi, int t16, int r0) {
#pragma unroll
  for (int e = 0; e < 4; ++e) {
    int idx = t16 * 4 + e, i = idx >> 3, j = idx & 7;
    float s = 0.f;
#pragma unroll
    for (int b = 0; b < 32; ++b) s = fmaf(YT_(mi, b, i), YT_(mi, b, j), s);
    SS_(mi, idx) = s;
  }
  __syncthreads();
  float Rl[36];
  chol8(Sm, mi, Rl);
  trsm2rows(Sm, Sm, mi, r0, Rl);
  __syncthreads();
}

// ============ Kernel 1: per-m Gram G=A^T A + Y0=A^T Omega, then small solve -> M = Q2 Q2^T ============
__global__ __launch_bounds__(256) void tsvd_k1(const float* __restrict__ x,
                                               const float* __restrict__ omega,
                                               float* __restrict__ Mws) {
  __shared__ float Sm[SMEMF];
  const int t = threadIdx.x;
  const int mi = t & 15, t16 = t >> 4;
  const int r0 = 2 * t16, r1 = r0 + 1;
  const int m0 = blockIdx.x * TM;

  float G0[32], G1[32], Y00[8], Y01[8];
#pragma unroll
  for (int b = 0; b < 32; ++b) { G0[b] = 0.f; G1[b] = 0.f; }
#pragma unroll
  for (int q = 0; q < 8; ++q) { Y00[q] = 0.f; Y01[q] = 0.f; }

  // ---- phase A: stream c in chunks, accumulate G rows r0,r1 and Y0 rows r0,r1 ----
  float4 st[4];
  stage_load(st, x, 0, m0, t);
  stage_write(st, Sm, t);
  for (int ch = 0; ch < NC / CC; ++ch) {
    if (ch + 1 < NC / CC) stage_load(st, x, (ch + 1) * CC, m0, t);
    __syncthreads();
    const float* cur = Sm + (ch & 1) * SLABF;
#pragma unroll
    for (int cc = 0; cc < CC; ++cc) {
      int c = ch * CC + cc;
      float w[8];
#pragma unroll
      for (int q = 0; q < 8; ++q) w[q] = omega[c * 8 + q];   // uniform -> s_load
      const float* v = cur + cc * (NB * TM) + mi;
      float vr0 = v[r0 * TM], vr1 = v[r1 * TM];
#pragma unroll
      for (int b = 0; b < 32; ++b) {
        float vb = v[b * TM];                                 // 16-bank broadcast read
        G0[b] = fmaf(vr0, vb, G0[b]);
        G1[b] = fmaf(vr1, vb, G1[b]);
      }
#pragma unroll
      for (int q = 0; q < 8; ++q) {
        Y00[q] = fmaf(vr0, w[q], Y00[q]);
        Y01[q] = fmaf(vr1, w[q], Y01[q]);
      }
    }
    if (ch + 1 < NC / CC) stage_write(st, Sm + ((ch + 1) & 1) * SLABF, t);
  }
  __syncthreads();   // slab dead; phase-B buffers may now overwrite it

  // ---- phase B: small per-m solve (all in LDS + registers) ----
  // B1: Y0 -> YT
#pragma unroll
  for (int q = 0; q < 8; ++q) { YT_(mi, r0, q) = Y00[q]; YT_(mi, r1, q) = Y01[q]; }
  __syncthreads();

#pragma unroll
  for (int it = 0; it < 3; ++it) {
    cholqr_pass(Sm, mi, t16, r0);   // CholQR2: Q spans range(Y), orthonormal
    cholqr_pass(Sm, mi, t16, r0);
    if (it < 2) {
      // U = G*Q -> WT
#pragma unroll
      for (int q = 0; q < 8; ++q) {
        float u0 = 0.f, u1 = 0.f;
#pragma unroll
        for (int b = 0; b < 32; ++b) {
          float qb = YT_(mi, b, q);
          u0 = fmaf(G0[b], qb, u0);
          u1 = fmaf(G1[b], qb, u1);
        }
        WT_(mi, r0, q) = u0; WT_(mi, r1, q) = u1;
      }
      __syncthreads();
      // T = Q^T U = Q^T G Q -> SS
#pragma unroll
      for (int e = 0; e < 4; ++e) {
        int idx = t16 * 4 + e, i2 = idx >> 3, j2 = idx & 7;
        float s = 0.f;
#pragma unroll
        for (int b = 0; b < 32; ++b) s = fmaf(YT_(mi, b, i2), WT_(mi, b, j2), s);
        SS_(mi, idx) = s;
      }
      __syncthreads();
      // W = Q R^{-1} -> WT   (implicit qr(A*Q): Qc = A*W)
      {
        float Rl[36];
        chol8(Sm, mi, Rl);
        trsm2rows(Sm, Sm + 4240, mi, r0, Rl);
      }
      __syncthreads();
      // Y_next = G*W -> YT   (= A^T Qc)
#pragma unroll
      for (int q = 0; q < 8; ++q) {
        float u0 = 0.f, u1 = 0.f;
#pragma unroll
        for (int b = 0; b < 32; ++b) {
          float wb = WT_(mi, b, q);
          u0 = fmaf(G0[b], wb, u0);
          u1 = fmaf(G1[b], wb, u1);
        }
        YT_(mi, r0, q) = u0; YT_(mi, r1, q) = u1;
      }
      __syncthreads();
    }
  }

  // B5: M = Q2 Q2^T, stored m-contiguous: Mws[(b1*32+b2)*HW + m]
  float q0[8], q1[8];
#pragma unroll
  for (int qq = 0; qq < 8; ++qq) { q0[qq] = YT_(mi, r0, qq); q1[qq] = YT_(mi, r1, qq); }
  const int m = m0 + mi;
#pragma unroll
  for (int b2 = 0; b2 < 32; ++b2) {
    float a0 = 0.f, a1 = 0.f;
#pragma unroll
    for (int qq = 0; qq < 8; ++qq) {
      float z = YT_(mi, b2, qq);
      a0 = fmaf(q0[qq], z, a0);
      a1 = fmaf(q1[qq], z, a1);
    }
    Mws[(size_t)(r0 * 32 + b2) * HW + m] = a0;
    Mws[(size_t)(r1 * 32 + b2) * HW + m] = a1;
  }
}

// ============ Kernel 2: y[b][c][m] = sum_b' x[b'][c][m] * M[b'][b][m] ============
__global__ __launch_bounds__(256) void tsvd_k2(const float* __restrict__ x,
                                               const float* __restrict__ Mws,
                                               float* __restrict__ y) {
  __shared__ float slab[2 * SLABF];
  const int t = threadIdx.x;
  const int mi = t & 15, t16 = t >> 4;
  const int r0 = 2 * t16, r1 = r0 + 1;
  const int bid = blockIdx.x;
  const int mt = bid % 196, cq = bid / 196;      // 196 m-tiles x 4 c-quarters
  const int m0 = mt * TM, m = m0 + mi;
  const int cbase = cq * 64;

  float M0[32], M1[32];   // columns r0, r1 of symmetric M (one per output b)
#pragma unroll
  for (int b = 0; b < 32; ++b) {
    M0[b] = Mws[(size_t)(b * 32 + r0) * HW + m];
    M1[b] = Mws[(size_t)(b * 32 + r1) * HW + m];
  }

  float4 st[4];
  stage_load(st, x, cbase, m0, t);
  stage_write(st, slab, t);
  for (int ch = 0; ch < 8; ++ch) {
    if (ch + 1 < 8) stage_load(st, x, cbase + (ch + 1) * CC, m0, t);
    __syncthreads();
    const float* cur = slab + (ch & 1) * SLABF;
#pragma unroll
    for (int cc = 0; cc < CC; ++cc) {
      int c = cbase + ch * CC + cc;
      const float* v = cur + cc * (NB * TM) + mi;
      float a0 = 0.f, a1 = 0.f;
#pragma unroll
      for (int b = 0; b < 32; ++b) {
        float vb = v[b * TM];
        a0 = fmaf(vb, M0[b], a0);
        a1 = fmaf(vb, M1[b], a1);
      }
      y[((size_t)r0 * NC + c) * HW + m] = a0;
      y[((size_t)r1 * NC + c) * HW + m] = a1;
    }
    if (ch + 1 < 8) stage_write(st, slab + ((ch + 1) & 1) * SLABF, t);
  }
}

extern "C" void kernel_launch(void* const* d_in, const int* in_sizes, int n_in,
                              void* d_out, int out_size, void* d_ws, size_t ws_size,
                              hipStream_t stream) {
  const float* x     = (const float*)d_in[0];   // 32*256*3136 fp32
  const float* omega = (const float*)d_in[1];   // 256*8 fp32
  float* y   = (float*)d_out;                   // 32*256*3136 fp32
  float* Mws = (float*)d_ws;                    // needs 1024*3136*4 = 12.85 MB

  tsvd_k1<<<HW / TM, 256, 0, stream>>>(x, omega, Mws);
  tsvd_k2<<<(HW / TM) * 4, 256, 0, stream>>>(x, Mws, y);
}